// Round 9
// baseline (794.707 us; speedup 1.0000x reference)
//
#include <hip/hip_runtime.h>
#include <hip/hip_bf16.h>

#define NTOK 4096
#define DEMB 1024
#define NH   8
#define DH   128
#define CWIN 256
#define QKVW 384
#define SCALE 0.08838834764831845f   // 1/sqrt(128)
#define QT 8                          // tokens per block (rows 0-7 valid, 8-15 quarantined)
#define NCH 34                        // 16-key chunks covering the <=520-wide band

typedef __attribute__((ext_vector_type(8))) short short8;
typedef __attribute__((ext_vector_type(4))) float floatx4;

__device__ __forceinline__ short8 pack8(float4 a, float4 b) {
    union { __hip_bfloat16 h[8]; short8 v; } o;
    o.h[0] = __float2bfloat16(a.x); o.h[1] = __float2bfloat16(a.y);
    o.h[2] = __float2bfloat16(a.z); o.h[3] = __float2bfloat16(a.w);
    o.h[4] = __float2bfloat16(b.x); o.h[5] = __float2bfloat16(b.y);
    o.h[6] = __float2bfloat16(b.z); o.h[7] = __float2bfloat16(b.w);
    return o.v;
}

// ---------------- weight prep (once per call) ----------------
__global__ void pack_wqkv(const float* __restrict__ Wq, const float* __restrict__ Wk,
                          const float* __restrict__ Wvd, __hip_bfloat16* __restrict__ dst) {
    size_t base = ((size_t)blockIdx.x * 256 + threadIdx.x) * 8;
    int k = (int)(base & 1023);
    int rh = (int)(base >> 10);
    int h = rh / QKVW;
    int row = rh - h * QKVW;
    const float* srcs[3] = {Wq, Wk, Wvd};
    const float* s = srcs[row >> 7] + (((size_t)h * DH + (row & 127)) << 10) + k;
    *(short8*)(dst + base) = pack8(*(const float4*)s, *(const float4*)(s + 4));
}

__global__ void pack_wvu(const float* __restrict__ Wvu, __hip_bfloat16* __restrict__ dst) {
    size_t base = ((size_t)blockIdx.x * 256 + threadIdx.x) * 8;
    *(short8*)(dst + base) = pack8(*(const float4*)(Wvu + base), *(const float4*)(Wvu + base + 4));
}

// ---------------- stage 0: e = x (+ bf16 mirror for head-0 qkv) -----------
__global__ void init_e(const float4* __restrict__ x, float4* __restrict__ e,
                       __hip_bfloat16* __restrict__ ebf) {
    int i = blockIdx.x * 256 + threadIdx.x;
    float4 v = x[i];
    e[i] = v;
    union { __hip_bfloat16 h[4]; uint2 u; } p;
    p.h[0] = __float2bfloat16(v.x); p.h[1] = __float2bfloat16(v.y);
    p.h[2] = __float2bfloat16(v.z); p.h[3] = __float2bfloat16(v.w);
    *(uint2*)(ebf + (size_t)i * 4) = p.u;
}

// ---------------- head-0 qkv GEMM: emits Q (scaled), K, V^T ---------------
__global__ __launch_bounds__(256) void qkv_gemm_mfma(const __hip_bfloat16* __restrict__ A,
                                                     const __hip_bfloat16* __restrict__ B,
                                                     __hip_bfloat16* __restrict__ Qb,
                                                     __hip_bfloat16* __restrict__ Kb,
                                                     __hip_bfloat16* __restrict__ Vtb) {
    constexpr int K = DEMB;
    constexpr int LDK = 40;
    const int c0 = blockIdx.x * 64, r0 = blockIdx.y * 64;
    const int tid = threadIdx.x;
    const int wave = tid >> 6, lane = tid & 63;
    const int wr = (wave >> 1) * 32, wc = (wave & 1) * 32;
    const int frow = lane & 15, kgrp = (lane >> 4) * 8;
    const int quad = lane >> 4;
    const int sr = tid >> 2, sk = (tid & 3) * 8;

    __shared__ __hip_bfloat16 As[64 * LDK];
    __shared__ __hip_bfloat16 Bs[64 * LDK];

    floatx4 acc[2][2] = {};

    for (int k0 = 0; k0 < K; k0 += 32) {
        __syncthreads();
        *(short8*)(As + sr * LDK + sk) = *(const short8*)(A + (size_t)(r0 + sr) * K + k0 + sk);
        *(short8*)(Bs + sr * LDK + sk) = *(const short8*)(B + (size_t)(c0 + sr) * K + k0 + sk);
        __syncthreads();
        short8 a0 = *(const short8*)(As + (wr + frow) * LDK + kgrp);
        short8 a1 = *(const short8*)(As + (wr + 16 + frow) * LDK + kgrp);
        short8 b0 = *(const short8*)(Bs + (wc + frow) * LDK + kgrp);
        short8 b1 = *(const short8*)(Bs + (wc + 16 + frow) * LDK + kgrp);
        acc[0][0] = __builtin_amdgcn_mfma_f32_16x16x32_bf16(a0, b0, acc[0][0], 0, 0, 0);
        acc[0][1] = __builtin_amdgcn_mfma_f32_16x16x32_bf16(a0, b1, acc[0][1], 0, 0, 0);
        acc[1][0] = __builtin_amdgcn_mfma_f32_16x16x32_bf16(a1, b0, acc[1][0], 0, 0, 0);
        acc[1][1] = __builtin_amdgcn_mfma_f32_16x16x32_bf16(a1, b1, acc[1][1], 0, 0, 0);
    }

    #pragma unroll
    for (int i = 0; i < 2; i++)
        #pragma unroll
        for (int j = 0; j < 2; j++) {
            int col = c0 + wc + j * 16 + frow;
            int row0 = r0 + wr + i * 16 + quad * 4;
            if (col < DH) {
                #pragma unroll
                for (int r = 0; r < 4; r++)
                    Qb[(size_t)(row0 + r) * DH + col] = __float2bfloat16(acc[i][j][r] * SCALE);
            } else if (col < 2 * DH) {
                #pragma unroll
                for (int r = 0; r < 4; r++)
                    Kb[(size_t)(row0 + r) * DH + col - DH] = __float2bfloat16(acc[i][j][r]);
            } else {
                union { __hip_bfloat16 h[4]; uint2 u; } p;
                #pragma unroll
                for (int r = 0; r < 4; r++) p.h[r] = __float2bfloat16(acc[i][j][r]);
                *(uint2*)(Vtb + (size_t)(col - 2 * DH) * NTOK + row0) = p.u;
            }
        }
}

// ---------------- fused head kernel, QT=8 / 256 threads / grid 512 --------
// 2 blocks/CU (independent barrier groups) to fill phase-drain stalls.
// MFMA M=16 but only rows 0-7 valid; rows 8-15 are zero/quarantined (MFMA is
// row-separable; P rows 8-15 = 0, linv = 0, all global writes guarded).
// OOB band-edge fragment reads land in adjacent ws buffers: finite bf16,
// multiplied by p=0.
__global__ __launch_bounds__(256, 2) void attn_head(const __hip_bfloat16* __restrict__ Qb,
                                                    const __hip_bfloat16* __restrict__ Kb,
                                                    const __hip_bfloat16* __restrict__ Vtb,
                                                    __hip_bfloat16* __restrict__ Qn,
                                                    __hip_bfloat16* __restrict__ Kn,
                                                    __hip_bfloat16* __restrict__ Vtn,
                                                    const __hip_bfloat16* __restrict__ Wqkv_nxt,
                                                    const __hip_bfloat16* __restrict__ Wvu,
                                                    float* __restrict__ e,
                                                    float* __restrict__ out_final) {
    // XCD swizzle: token-contiguous groups of 64 blocks share an XCD (L2 locality
    // for band K/V, which the same token group produced last head).
    const int vb = ((blockIdx.x & 7) << 6) | (blockIdx.x >> 3);
    const int q0 = vb * QT;
    const int tid = threadIdx.x;
    const int wave = tid >> 6, lane = tid & 63;
    const int fr = lane & 15, kg = (lane >> 4) * 8;
    const int quad = lane >> 4;
    const bool rowok = (quad < 2);            // rows quad*4+r in [0,8)
    const bool last = (out_final != nullptr);

    __shared__ alignas(16) __hip_bfloat16 Qs[16][DH + 8];      // Q tile; later u rows
    __shared__ alignas(16) __hip_bfloat16 Pb[16][NCH * 16 + 8];
    __shared__ alignas(16) __hip_bfloat16 Ebs[16][DEMB + 8];   // bf16 res rows (tail A)
    __shared__ float statsA[QT][4];
    __shared__ float statsB[QT][4];

    // stage Q rows 0-7; zero rows 8-15; zero Ebs rows 8-15
    {
        int r = tid >> 4, c8 = (tid & 15) * 8;
        if (r < 8) {
            *(short8*)&Qs[r][c8] = *(const short8*)(Qb + (size_t)(q0 + r) * DH + c8);
        } else {
            short8 z = {};
            *(short8*)&Qs[r][c8] = z;
        }
        short8 z = {};
        for (int idx = tid; idx < 1032; idx += 256) {
            int rr = 8 + idx / 129, cc = (idx % 129) * 8;
            *(short8*)&Ebs[rr][cc] = z;
        }
    }
    __syncthreads();
    short8 af[4];
    #pragma unroll
    for (int kc = 0; kc < 4; kc++) af[kc] = *(const short8*)&Qs[fr][kc * 32 + kg];

    const int kstart = max(q0 - CWIN, 0);
    const int kend   = min(q0 + QT - 1 + CWIN + 1, NTOK);
    const int nch = (wave < 2) ? 9 : 8;       // chunks ch = wave + 4t, ch < 34

    // ---- scores: wave's chunks, K fragments straight from L2 -------------
    floatx4 sreg[9];
    #pragma unroll
    for (int t = 0; t < 9; t++) {
        if (t >= nch) break;
        int ch = wave + 4 * t;
        const __hip_bfloat16* krow = Kb + (size_t)(kstart + ch * 16 + fr) * DH;
        floatx4 s = {};
        #pragma unroll
        for (int kc = 0; kc < 4; kc++)
            s = __builtin_amdgcn_mfma_f32_16x16x32_bf16(af[kc],
                    *(const short8*)(krow + kc * 32 + kg), s, 0, 0, 0);
        sreg[t] = s;
    }

    // ---- band mask + per-row max ------------------------------------------
    float pmax[4] = {-1e30f, -1e30f, -1e30f, -1e30f};
    #pragma unroll
    for (int t = 0; t < 9; t++) {
        if (t >= nch) break;
        int tcol = kstart + (wave + 4 * t) * 16 + fr;
        #pragma unroll
        for (int r = 0; r < 4; r++) {
            int qg = q0 + quad * 4 + r;
            bool ok = rowok && (tcol < kend) && (tcol >= qg - CWIN) && (tcol < qg + CWIN);
            float v = ok ? sreg[t][r] : -1e30f;
            sreg[t][r] = v;
            pmax[r] = fmaxf(pmax[r], v);
        }
    }
    #pragma unroll
    for (int mm = 1; mm <= 8; mm <<= 1)
        #pragma unroll
        for (int r = 0; r < 4; r++) pmax[r] = fmaxf(pmax[r], __shfl_xor(pmax[r], mm, 64));
    if (rowok && fr == 0)
        #pragma unroll
        for (int r = 0; r < 4; r++) statsA[quad * 4 + r][wave] = pmax[r];
    __syncthreads();

    float M[4] = {};
    if (rowok)
        #pragma unroll
        for (int r = 0; r < 4; r++) {
            int row = quad * 4 + r;
            float m = statsA[row][0];
            #pragma unroll
            for (int w = 1; w < 4; w++) m = fmaxf(m, statsA[row][w]);
            M[r] = m;
        }

    // ---- exp -> Pb (A-layout), row sums -----------------------------------
    float psum[4] = {};
    #pragma unroll
    for (int t = 0; t < 9; t++) {
        if (t >= nch) break;
        int colb = (wave + 4 * t) * 16 + fr;
        #pragma unroll
        for (int r = 0; r < 4; r++) {
            float p = rowok ? __expf(sreg[t][r] - M[r]) : 0.f;
            psum[r] += p;
            Pb[quad * 4 + r][colb] = __float2bfloat16(p);
        }
    }
    #pragma unroll
    for (int mm = 1; mm <= 8; mm <<= 1)
        #pragma unroll
        for (int r = 0; r < 4; r++) psum[r] += __shfl_xor(psum[r], mm, 64);
    if (rowok && fr == 0)
        #pragma unroll
        for (int r = 0; r < 4; r++) statsB[quad * 4 + r][wave] = psum[r];
    __syncthreads();

    float linv[4] = {};
    if (rowok)
        #pragma unroll
        for (int r = 0; r < 4; r++) {
            int row = quad * 4 + r;
            float s = statsB[row][0] + statsB[row][1] + statsB[row][2] + statsB[row][3];
            linv[r] = 1.0f / s;
        }

    // ---- PV: wave owns dims [32w,32w+32); Vt fragments from L2 ------------
    floatx4 Of[2] = {};
    #pragma unroll
    for (int kc = 0; kc < NCH / 2; kc++) {
        short8 pf = *(const short8*)&Pb[fr][kc * 32 + kg];
        #pragma unroll
        for (int sx = 0; sx < 2; sx++) {
            const __hip_bfloat16* vrow = Vtb + (size_t)(wave * 32 + sx * 16 + fr) * NTOK
                                       + kstart + kc * 32 + kg;
            Of[sx] = __builtin_amdgcn_mfma_f32_16x16x32_bf16(pf, *(const short8*)vrow,
                                                             Of[sx], 0, 0, 0);
        }
    }

    // ---- u rows -> Qs overlay (A-layout for out-proj) ---------------------
    #pragma unroll
    for (int sx = 0; sx < 2; sx++) {
        int col = wave * 32 + sx * 16 + fr;
        #pragma unroll
        for (int r = 0; r < 4; r++)
            Qs[quad * 4 + r][col] = __float2bfloat16(Of[sx][r] * linv[r]);  // rows 8-15: *0 = 0
    }
    __syncthreads();
    short8 af2[4];
    #pragma unroll
    for (int kc = 0; kc < 4; kc++) af2[kc] = *(const short8*)&Qs[fr][kc * 32 + kg];

    // ---- out-proj: wave owns cols [256w,256w+256); Wvu from L2 ------------
    floatx4 accd[16] = {};
    #pragma unroll
    for (int n0 = 0; n0 < 16; n0++) {
        const __hip_bfloat16* wrow = Wvu + ((size_t)(wave * 256 + n0 * 16 + fr) << 7);
        #pragma unroll
        for (int kc = 0; kc < 4; kc++)
            accd[n0] = __builtin_amdgcn_mfma_f32_16x16x32_bf16(af2[kc],
                           *(const short8*)(wrow + kc * 32 + kg), accd[n0], 0, 0, 0);
    }

    // ---- norm stats (e rows kept in registers) ----------------------------
    floatx4 eo[16];
    float s1[4] = {}, s2[4] = {};
    if (rowok) {
        #pragma unroll
        for (int n0 = 0; n0 < 16; n0++) {
            int col = wave * 256 + n0 * 16 + fr;
            #pragma unroll
            for (int r = 0; r < 4; r++) {
                float ev = e[(size_t)(q0 + quad * 4 + r) * DEMB + col];
                eo[n0][r] = ev;
                float od = ev + accd[n0][r];
                s1[r] += od; s2[r] += od * od;
            }
        }
    }
    #pragma unroll
    for (int mm = 1; mm <= 8; mm <<= 1)
        #pragma unroll
        for (int r = 0; r < 4; r++) {
            s1[r] += __shfl_xor(s1[r], mm, 64);
            s2[r] += __shfl_xor(s2[r], mm, 64);
        }
    if (rowok && fr == 0)
        #pragma unroll
        for (int r = 0; r < 4; r++) {
            statsA[quad * 4 + r][wave] = s1[r];
            statsB[quad * 4 + r][wave] = s2[r];
        }
    __syncthreads();

    if (rowok) {
        float im0[4], mm_[4], isd[4];
        #pragma unroll
        for (int r = 0; r < 4; r++) {
            int row = quad * 4 + r;
            float S1 = statsA[row][0] + statsA[row][1] + statsA[row][2] + statsA[row][3];
            float S2 = statsB[row][0] + statsB[row][1] + statsB[row][2] + statsB[row][3];
            float m0 = S1 * (1.0f / DEMB);
            float iv = 1.0f / m0;
            float m  = m0 * iv;                    // mean(out/m0) ~ 1
            float st = S1 * iv;
            float var = (S2 * iv * iv - st * st * (1.0f / DEMB)) * (1.0f / (DEMB - 1));
            im0[r] = iv; mm_[r] = m; isd[r] = rsqrtf(var);
        }
        #pragma unroll
        for (int n0 = 0; n0 < 16; n0++) {
            int col = wave * 256 + n0 * 16 + fr;
            #pragma unroll
            for (int r = 0; r < 4; r++) {
                float ev = eo[n0][r];
                float t = (ev + accd[n0][r]) * im0[r];
                float res = ev + (t - mm_[r]) * isd[r] + mm_[r];
                size_t idx = (size_t)(q0 + quad * 4 + r) * DEMB + col;
                if (last) {
                    out_final[idx] = res * 0.125f;
                } else {
                    e[idx] = res;
                    Ebs[quad * 4 + r][col] = __float2bfloat16(res);
                }
            }
        }
    }

    // ---- fused next-head QKV: 24 N-tiles over 4 waves (6 each) ------------
    if (!last) {
        __syncthreads();               // Ebs complete (rows 8-15 zeroed at start)
        floatx4 acc6[6] = {};
        const int n0t = 6 * wave;
        const __hip_bfloat16* wbase = Wqkv_nxt + (size_t)(n0t * 16 + fr) * DEMB + kg;
        #pragma unroll 8
        for (int kc = 0; kc < 32; kc++) {
            short8 a = *(const short8*)&Ebs[fr][kc * 32 + kg];
            #pragma unroll
            for (int t = 0; t < 6; t++)
                acc6[t] = __builtin_amdgcn_mfma_f32_16x16x32_bf16(a,
                              *(const short8*)(wbase + (size_t)t * 16 * DEMB + kc * 32),
                              acc6[t], 0, 0, 0);
        }
        if (rowok) {
            const int row0 = q0 + quad * 4;
            #pragma unroll
            for (int t = 0; t < 6; t++) {
                int n = n0t + t;
                if (n < 8) {               // Q, pre-scaled
                    int col = n * 16 + fr;
                    #pragma unroll
                    for (int rr = 0; rr < 4; rr++)
                        Qn[(size_t)(row0 + rr) * DH + col] = __float2bfloat16(acc6[t][rr] * SCALE);
                } else if (n < 16) {       // K
                    int col = (n - 8) * 16 + fr;
                    #pragma unroll
                    for (int rr = 0; rr < 4; rr++)
                        Kn[(size_t)(row0 + rr) * DH + col] = __float2bfloat16(acc6[t][rr]);
                } else {                   // V^T
                    int d = (n - 16) * 16 + fr;
                    union { __hip_bfloat16 h[4]; uint2 u; } p;
                    #pragma unroll
                    for (int rr = 0; rr < 4; rr++) p.h[rr] = __float2bfloat16(acc6[t][rr]);
                    *(uint2*)(Vtn + (size_t)d * NTOK + row0) = p.u;
                }
            }
        }
    }
}

extern "C" void kernel_launch(void* const* d_in, const int* in_sizes, int n_in,
                              void* d_out, int out_size, void* d_ws, size_t ws_size,
                              hipStream_t stream) {
    const float* x   = (const float*)d_in[0];
    const float* Wq  = (const float*)d_in[1];
    const float* Wk  = (const float*)d_in[2];
    const float* Wvd = (const float*)d_in[3];
    const float* Wvu = (const float*)d_in[4];

    char* ws = (char*)d_ws;
    float* e = (float*)ws;                                              // 16 MB
    __hip_bfloat16* ebf   = (__hip_bfloat16*)(ws + (16u << 20));        //  8 MB (head-0 prologue only)
    __hip_bfloat16* Qb[2] = {(__hip_bfloat16*)(ws + (24u << 20)),
                             (__hip_bfloat16*)(ws + (27u << 20))};      //  1 MB each
    __hip_bfloat16* Kb[2] = {(__hip_bfloat16*)(ws + (25u << 20)),
                             (__hip_bfloat16*)(ws + (28u << 20))};
    __hip_bfloat16* Vt[2] = {(__hip_bfloat16*)(ws + (26u << 20)),
                             (__hip_bfloat16*)(ws + (29u << 20))};
    __hip_bfloat16* wqkvb = (__hip_bfloat16*)(ws + (30u << 20));        //  6 MB
    __hip_bfloat16* wvub  = (__hip_bfloat16*)(ws + (36u << 20));        //  2 MB  -> 38 MB

    pack_wqkv<<<NH * QKVW * DEMB / 8 / 256, 256, 0, stream>>>(Wq, Wk, Wvd, wqkvb);
    pack_wvu<<<NH * DEMB * DH / 8 / 256, 256, 0, stream>>>(Wvu, wvub);
    init_e<<<NTOK * DEMB / 4 / 256, 256, 0, stream>>>((const float4*)x, (float4*)e, ebf);

    qkv_gemm_mfma<<<dim3(QKVW / 64, NTOK / 64), 256, 0, stream>>>(
        ebf, wqkvb, Qb[0], Kb[0], Vt[0]);

    for (int h = 0; h < NH; h++) {
        int cur = h & 1, nxt = 1 - cur;
        attn_head<<<NTOK / QT, 256, 0, stream>>>(
            Qb[cur], Kb[cur], Vt[cur],
            Qb[nxt], Kb[nxt], Vt[nxt],
            wqkvb + (size_t)((h + 1 < NH) ? h + 1 : 0) * QKVW * DEMB,
            wvub + (size_t)h * DEMB * DH, e,
            (h == NH - 1) ? (float*)d_out : nullptr);
    }
}

// Round 10
// 472.413 us; speedup vs baseline: 1.6822x; 1.6822x over previous
//
#include <hip/hip_runtime.h>
#include <hip/hip_bf16.h>

#define NTOK 4096
#define DEMB 1024
#define NH   8
#define DH   128
#define CWIN 256
#define QKVW 384
#define SCALE 0.08838834764831845f   // 1/sqrt(128)
#define QT 16
#define NCH 34                        // 16-key chunks covering the <=527-wide band

typedef __attribute__((ext_vector_type(8))) short short8;
typedef __attribute__((ext_vector_type(4))) float floatx4;

__device__ __forceinline__ short8 pack8(float4 a, float4 b) {
    union { __hip_bfloat16 h[8]; short8 v; } o;
    o.h[0] = __float2bfloat16(a.x); o.h[1] = __float2bfloat16(a.y);
    o.h[2] = __float2bfloat16(a.z); o.h[3] = __float2bfloat16(a.w);
    o.h[4] = __float2bfloat16(b.x); o.h[5] = __float2bfloat16(b.y);
    o.h[6] = __float2bfloat16(b.z); o.h[7] = __float2bfloat16(b.w);
    return o.v;
}

// ---------------- weight prep (once per call) ----------------
__global__ void pack_wqkv(const float* __restrict__ Wq, const float* __restrict__ Wk,
                          const float* __restrict__ Wvd, __hip_bfloat16* __restrict__ dst) {
    size_t base = ((size_t)blockIdx.x * 256 + threadIdx.x) * 8;
    int k = (int)(base & 1023);
    int rh = (int)(base >> 10);
    int h = rh / QKVW;
    int row = rh - h * QKVW;
    const float* srcs[3] = {Wq, Wk, Wvd};
    const float* s = srcs[row >> 7] + (((size_t)h * DH + (row & 127)) << 10) + k;
    *(short8*)(dst + base) = pack8(*(const float4*)s, *(const float4*)(s + 4));
}

__global__ void pack_wvu(const float* __restrict__ Wvu, __hip_bfloat16* __restrict__ dst) {
    size_t base = ((size_t)blockIdx.x * 256 + threadIdx.x) * 8;
    *(short8*)(dst + base) = pack8(*(const float4*)(Wvu + base), *(const float4*)(Wvu + base + 4));
}

// ---------------- stage 0: e = x (+ bf16 mirror for head-0 qkv) -----------
__global__ void init_e(const float4* __restrict__ x, float4* __restrict__ e,
                       __hip_bfloat16* __restrict__ ebf) {
    int i = blockIdx.x * 256 + threadIdx.x;
    float4 v = x[i];
    e[i] = v;
    union { __hip_bfloat16 h[4]; uint2 u; } p;
    p.h[0] = __float2bfloat16(v.x); p.h[1] = __float2bfloat16(v.y);
    p.h[2] = __float2bfloat16(v.z); p.h[3] = __float2bfloat16(v.w);
    *(uint2*)(ebf + (size_t)i * 4) = p.u;
}

// ---------------- head-0 qkv GEMM: emits Q (scaled), K, V^T ---------------
__global__ __launch_bounds__(256) void qkv_gemm_mfma(const __hip_bfloat16* __restrict__ A,
                                                     const __hip_bfloat16* __restrict__ B,
                                                     __hip_bfloat16* __restrict__ Qb,
                                                     __hip_bfloat16* __restrict__ Kb,
                                                     __hip_bfloat16* __restrict__ Vtb) {
    constexpr int K = DEMB;
    constexpr int LDK = 40;
    const int c0 = blockIdx.x * 64, r0 = blockIdx.y * 64;
    const int tid = threadIdx.x;
    const int wave = tid >> 6, lane = tid & 63;
    const int wr = (wave >> 1) * 32, wc = (wave & 1) * 32;
    const int frow = lane & 15, kgrp = (lane >> 4) * 8;
    const int quad = lane >> 4;
    const int sr = tid >> 2, sk = (tid & 3) * 8;

    __shared__ __hip_bfloat16 As[64 * LDK];
    __shared__ __hip_bfloat16 Bs[64 * LDK];

    floatx4 acc[2][2] = {};

    for (int k0 = 0; k0 < K; k0 += 32) {
        __syncthreads();
        *(short8*)(As + sr * LDK + sk) = *(const short8*)(A + (size_t)(r0 + sr) * K + k0 + sk);
        *(short8*)(Bs + sr * LDK + sk) = *(const short8*)(B + (size_t)(c0 + sr) * K + k0 + sk);
        __syncthreads();
        short8 a0 = *(const short8*)(As + (wr + frow) * LDK + kgrp);
        short8 a1 = *(const short8*)(As + (wr + 16 + frow) * LDK + kgrp);
        short8 b0 = *(const short8*)(Bs + (wc + frow) * LDK + kgrp);
        short8 b1 = *(const short8*)(Bs + (wc + 16 + frow) * LDK + kgrp);
        acc[0][0] = __builtin_amdgcn_mfma_f32_16x16x32_bf16(a0, b0, acc[0][0], 0, 0, 0);
        acc[0][1] = __builtin_amdgcn_mfma_f32_16x16x32_bf16(a0, b1, acc[0][1], 0, 0, 0);
        acc[1][0] = __builtin_amdgcn_mfma_f32_16x16x32_bf16(a1, b0, acc[1][0], 0, 0, 0);
        acc[1][1] = __builtin_amdgcn_mfma_f32_16x16x32_bf16(a1, b1, acc[1][1], 0, 0, 0);
    }

    #pragma unroll
    for (int i = 0; i < 2; i++)
        #pragma unroll
        for (int j = 0; j < 2; j++) {
            int col = c0 + wc + j * 16 + frow;
            int row0 = r0 + wr + i * 16 + quad * 4;
            if (col < DH) {
                #pragma unroll
                for (int r = 0; r < 4; r++)
                    Qb[(size_t)(row0 + r) * DH + col] = __float2bfloat16(acc[i][j][r] * SCALE);
            } else if (col < 2 * DH) {
                #pragma unroll
                for (int r = 0; r < 4; r++)
                    Kb[(size_t)(row0 + r) * DH + col - DH] = __float2bfloat16(acc[i][j][r]);
            } else {
                union { __hip_bfloat16 h[4]; uint2 u; } p;
                #pragma unroll
                for (int r = 0; r < 4; r++) p.h[r] = __float2bfloat16(acc[i][j][r]);
                *(uint2*)(Vtb + (size_t)(col - 2 * DH) * NTOK + row0) = p.u;
            }
        }
}

// ---------------- fused head kernel: QT=16, 1024 threads (16 waves) -------
// Same work as the round-8 kernel, split 2x finer across waves: 16 waves/CU
// (4/SIMD) for latency hiding inside each barrier phase. PV is split into
// two kc-halves combined through LDS. OOB band-edge fragment reads land in
// adjacent ws buffers: finite bf16, multiplied by p=0.
__global__ __launch_bounds__(1024, 4) void attn_head(const __hip_bfloat16* __restrict__ Qb,
                                                     const __hip_bfloat16* __restrict__ Kb,
                                                     const __hip_bfloat16* __restrict__ Vtb,
                                                     __hip_bfloat16* __restrict__ Qn,
                                                     __hip_bfloat16* __restrict__ Kn,
                                                     __hip_bfloat16* __restrict__ Vtn,
                                                     const __hip_bfloat16* __restrict__ Wqkv_nxt,
                                                     const __hip_bfloat16* __restrict__ Wvu,
                                                     float* __restrict__ e,
                                                     float* __restrict__ out_final) {
    // XCD swizzle: 32 token-contiguous blocks per XCD (band K/V L2 locality,
    // matching the producer blocks of the previous head).
    const int vb = ((blockIdx.x & 7) << 5) | (blockIdx.x >> 3);
    const int q0 = vb * QT;
    const int tid = threadIdx.x;
    const int wave = tid >> 6, lane = tid & 63;
    const int fr = lane & 15, kg = (lane >> 4) * 8;
    const int quad = lane >> 4;
    const bool last = (out_final != nullptr);

    __shared__ alignas(16) __hip_bfloat16 Qs[QT][DH + 8];      // Q tile; later u rows
    __shared__ alignas(16) __hip_bfloat16 Pb[QT][NCH * 16 + 8];
    __shared__ alignas(16) __hip_bfloat16 Ebs[QT][DEMB + 8];   // bf16 res rows (tail A)
    __shared__ alignas(16) float Opart[8][64][4];              // PV partial (kc-half 1)
    __shared__ float statsA[QT][16];
    __shared__ float statsB[QT][16];

    if (tid < 256) {   // stage Q (16x128 bf16)
        int r = tid >> 4, c8 = (tid & 15) * 8;
        *(short8*)&Qs[r][c8] = *(const short8*)(Qb + (size_t)(q0 + r) * DH + c8);
    }
    __syncthreads();
    short8 af[4];
    #pragma unroll
    for (int kc = 0; kc < 4; kc++) af[kc] = *(const short8*)&Qs[fr][kc * 32 + kg];

    const int kstart = max(q0 - CWIN, 0);
    const int kend   = min(q0 + QT - 1 + CWIN + 1, NTOK);
    const int nch = (wave < 2) ? 3 : 2;       // chunks ch = wave + 16t, ch < 34

    // ---- scores: wave's 2-3 chunks, K fragments straight from L2 ---------
    floatx4 sreg[3];
    #pragma unroll
    for (int t = 0; t < 3; t++) {
        if (t >= nch) break;
        int ch = wave + 16 * t;
        const __hip_bfloat16* krow = Kb + (size_t)(kstart + ch * 16 + fr) * DH;
        short8 kf0 = *(const short8*)(krow);
        short8 kf1 = *(const short8*)(krow + 32 + kg - kg + 32);   // kc=1 base
        floatx4 s = {};
        s = __builtin_amdgcn_mfma_f32_16x16x32_bf16(af[0], *(const short8*)(krow + 0 * 32 + kg), s, 0, 0, 0);
        s = __builtin_amdgcn_mfma_f32_16x16x32_bf16(af[1], *(const short8*)(krow + 1 * 32 + kg), s, 0, 0, 0);
        s = __builtin_amdgcn_mfma_f32_16x16x32_bf16(af[2], *(const short8*)(krow + 2 * 32 + kg), s, 0, 0, 0);
        s = __builtin_amdgcn_mfma_f32_16x16x32_bf16(af[3], *(const short8*)(krow + 3 * 32 + kg), s, 0, 0, 0);
        (void)kf0; (void)kf1;
        sreg[t] = s;
    }

    // ---- band mask + per-row max ------------------------------------------
    float pmax[4] = {-1e30f, -1e30f, -1e30f, -1e30f};
    #pragma unroll
    for (int t = 0; t < 3; t++) {
        if (t >= nch) break;
        int tcol = kstart + (wave + 16 * t) * 16 + fr;
        #pragma unroll
        for (int r = 0; r < 4; r++) {
            int qg = q0 + quad * 4 + r;
            bool ok = (tcol < kend) && (tcol >= qg - CWIN) && (tcol < qg + CWIN);
            float v = ok ? sreg[t][r] : -1e30f;
            sreg[t][r] = v;
            pmax[r] = fmaxf(pmax[r], v);
        }
    }
    #pragma unroll
    for (int mm = 1; mm <= 8; mm <<= 1)
        #pragma unroll
        for (int r = 0; r < 4; r++) pmax[r] = fmaxf(pmax[r], __shfl_xor(pmax[r], mm, 64));
    if (fr == 0)
        #pragma unroll
        for (int r = 0; r < 4; r++) statsA[quad * 4 + r][wave] = pmax[r];
    __syncthreads();

    float M[4];
    #pragma unroll
    for (int r = 0; r < 4; r++) {
        int row = quad * 4 + r;
        float m = statsA[row][0];
        #pragma unroll
        for (int w = 1; w < 16; w++) m = fmaxf(m, statsA[row][w]);
        M[r] = m;
    }

    // ---- exp -> Pb (A-layout), row sums -----------------------------------
    float psum[4] = {};
    #pragma unroll
    for (int t = 0; t < 3; t++) {
        if (t >= nch) break;
        int colb = (wave + 16 * t) * 16 + fr;
        #pragma unroll
        for (int r = 0; r < 4; r++) {
            float p = __expf(sreg[t][r] - M[r]);
            psum[r] += p;
            Pb[quad * 4 + r][colb] = __float2bfloat16(p);
        }
    }
    #pragma unroll
    for (int mm = 1; mm <= 8; mm <<= 1)
        #pragma unroll
        for (int r = 0; r < 4; r++) psum[r] += __shfl_xor(psum[r], mm, 64);
    if (fr == 0)
        #pragma unroll
        for (int r = 0; r < 4; r++) statsB[quad * 4 + r][wave] = psum[r];
    __syncthreads();

    // ---- PV split in two kc-halves: wave = half*8 + dim-group -------------
    // dim-group g owns dims [16g, 16g+16); half 0: kc 0..8, half 1: kc 9..16.
    const int g = wave & 7, half = wave >> 3;
    {
        floatx4 Of = {};
        const int kc0 = half ? 9 : 0, kc1 = half ? 17 : 9;
        for (int kc = kc0; kc < kc1; kc++) {
            short8 pf = *(const short8*)&Pb[fr][kc * 32 + kg];
            const __hip_bfloat16* vrow = Vtb + (size_t)(g * 16 + fr) * NTOK
                                       + kstart + kc * 32 + kg;
            Of = __builtin_amdgcn_mfma_f32_16x16x32_bf16(pf, *(const short8*)vrow, Of, 0, 0, 0);
        }
        if (half) *(float4*)&Opart[g][lane][0] = *(float4*)&Of;
        __syncthreads();
        if (!half) {
            float4 o2 = *(const float4*)&Opart[g][lane][0];
            float linv[4];
            #pragma unroll
            for (int r = 0; r < 4; r++) {
                int row = quad * 4 + r;
                float s = 0.f;
                #pragma unroll
                for (int w = 0; w < 16; w++) s += statsB[row][w];
                linv[r] = 1.0f / s;
            }
            int col = g * 16 + fr;
            Qs[quad * 4 + 0][col] = __float2bfloat16((Of[0] + o2.x) * linv[0]);
            Qs[quad * 4 + 1][col] = __float2bfloat16((Of[1] + o2.y) * linv[1]);
            Qs[quad * 4 + 2][col] = __float2bfloat16((Of[2] + o2.z) * linv[2]);
            Qs[quad * 4 + 3][col] = __float2bfloat16((Of[3] + o2.w) * linv[3]);
        }
    }
    __syncthreads();
    short8 af2[4];
    #pragma unroll
    for (int kc = 0; kc < 4; kc++) af2[kc] = *(const short8*)&Qs[fr][kc * 32 + kg];

    // ---- out-proj: wave owns cols [64w, 64w+64); Wvu from L2 --------------
    floatx4 accd[4] = {};
    #pragma unroll
    for (int n0 = 0; n0 < 4; n0++) {
        const __hip_bfloat16* wrow = Wvu + ((size_t)(wave * 64 + n0 * 16 + fr) << 7);
        #pragma unroll
        for (int kc = 0; kc < 4; kc++)
            accd[n0] = __builtin_amdgcn_mfma_f32_16x16x32_bf16(af2[kc],
                           *(const short8*)(wrow + kc * 32 + kg), accd[n0], 0, 0, 0);
    }

    // ---- norm stats (e rows kept in registers) ----------------------------
    floatx4 eo[4];
    float s1[4] = {}, s2[4] = {};
    #pragma unroll
    for (int n0 = 0; n0 < 4; n0++) {
        int col = wave * 64 + n0 * 16 + fr;
        #pragma unroll
        for (int r = 0; r < 4; r++) {
            float ev = e[(size_t)(q0 + quad * 4 + r) * DEMB + col];
            eo[n0][r] = ev;
            float od = ev + accd[n0][r];
            s1[r] += od; s2[r] += od * od;
        }
    }
    #pragma unroll
    for (int mm = 1; mm <= 8; mm <<= 1)
        #pragma unroll
        for (int r = 0; r < 4; r++) {
            s1[r] += __shfl_xor(s1[r], mm, 64);
            s2[r] += __shfl_xor(s2[r], mm, 64);
        }
    if (fr == 0)
        #pragma unroll
        for (int r = 0; r < 4; r++) {
            statsA[quad * 4 + r][wave] = s1[r];
            statsB[quad * 4 + r][wave] = s2[r];
        }
    __syncthreads();

    {
        float im0[4], mm_[4], isd[4];
        #pragma unroll
        for (int r = 0; r < 4; r++) {
            int row = quad * 4 + r;
            float S1 = 0.f, S2 = 0.f;
            #pragma unroll
            for (int w = 0; w < 16; w++) { S1 += statsA[row][w]; S2 += statsB[row][w]; }
            float m0 = S1 * (1.0f / DEMB);
            float iv = 1.0f / m0;
            float m  = m0 * iv;                    // mean(out/m0) ~ 1
            float st = S1 * iv;
            float var = (S2 * iv * iv - st * st * (1.0f / DEMB)) * (1.0f / (DEMB - 1));
            im0[r] = iv; mm_[r] = m; isd[r] = rsqrtf(var);
        }
        #pragma unroll
        for (int n0 = 0; n0 < 4; n0++) {
            int col = wave * 64 + n0 * 16 + fr;
            #pragma unroll
            for (int r = 0; r < 4; r++) {
                float ev = eo[n0][r];
                float t = (ev + accd[n0][r]) * im0[r];
                float res = ev + (t - mm_[r]) * isd[r] + mm_[r];
                size_t idx = (size_t)(q0 + quad * 4 + r) * DEMB + col;
                if (last) {
                    out_final[idx] = res * 0.125f;
                } else {
                    e[idx] = res;
                    Ebs[quad * 4 + r][col] = __float2bfloat16(res);
                }
            }
        }
    }

    // ---- fused next-head QKV: 24 N-tiles over 16 waves (1-2 each) ---------
    if (!last) {
        __syncthreads();               // Ebs complete
        const int nt = (wave < 8) ? 2 : 1;    // tiles n = wave + 16t, n < 24
        floatx4 acc2[2] = {};
        #pragma unroll 8
        for (int kc = 0; kc < 32; kc++) {
            short8 a = *(const short8*)&Ebs[fr][kc * 32 + kg];
            #pragma unroll
            for (int t = 0; t < 2; t++) {
                if (t >= nt) break;
                int n = wave + 16 * t;
                acc2[t] = __builtin_amdgcn_mfma_f32_16x16x32_bf16(a,
                              *(const short8*)(Wqkv_nxt + (size_t)(n * 16 + fr) * DEMB
                                               + kc * 32 + kg),
                              acc2[t], 0, 0, 0);
            }
        }
        const int row0 = q0 + quad * 4;
        #pragma unroll
        for (int t = 0; t < 2; t++) {
            if (t >= nt) break;
            int n = wave + 16 * t;
            if (n < 8) {               // Q, pre-scaled
                int col = n * 16 + fr;
                #pragma unroll
                for (int rr = 0; rr < 4; rr++)
                    Qn[(size_t)(row0 + rr) * DH + col] = __float2bfloat16(acc2[t][rr] * SCALE);
            } else if (n < 16) {       // K
                int col = (n - 8) * 16 + fr;
                #pragma unroll
                for (int rr = 0; rr < 4; rr++)
                    Kn[(size_t)(row0 + rr) * DH + col] = __float2bfloat16(acc2[t][rr]);
            } else {                   // V^T
                int d = (n - 16) * 16 + fr;
                union { __hip_bfloat16 h[4]; uint2 u; } p;
                #pragma unroll
                for (int rr = 0; rr < 4; rr++) p.h[rr] = __float2bfloat16(acc2[t][rr]);
                *(uint2*)(Vtn + (size_t)d * NTOK + row0) = p.u;
            }
        }
    }
}

extern "C" void kernel_launch(void* const* d_in, const int* in_sizes, int n_in,
                              void* d_out, int out_size, void* d_ws, size_t ws_size,
                              hipStream_t stream) {
    const float* x   = (const float*)d_in[0];
    const float* Wq  = (const float*)d_in[1];
    const float* Wk  = (const float*)d_in[2];
    const float* Wvd = (const float*)d_in[3];
    const float* Wvu = (const float*)d_in[4];

    char* ws = (char*)d_ws;
    float* e = (float*)ws;                                              // 16 MB
    __hip_bfloat16* ebf   = (__hip_bfloat16*)(ws + (16u << 20));        //  8 MB (head-0 prologue only)
    __hip_bfloat16* Qb[2] = {(__hip_bfloat16*)(ws + (24u << 20)),
                             (__hip_bfloat16*)(ws + (27u << 20))};      //  1 MB each
    __hip_bfloat16* Kb[2] = {(__hip_bfloat16*)(ws + (25u << 20)),
                             (__hip_bfloat16*)(ws + (28u << 20))};
    __hip_bfloat16* Vt[2] = {(__hip_bfloat16*)(ws + (26u << 20)),
                             (__hip_bfloat16*)(ws + (29u << 20))};
    __hip_bfloat16* wqkvb = (__hip_bfloat16*)(ws + (30u << 20));        //  6 MB
    __hip_bfloat16* wvub  = (__hip_bfloat16*)(ws + (36u << 20));        //  2 MB  -> 38 MB

    pack_wqkv<<<NH * QKVW * DEMB / 8 / 256, 256, 0, stream>>>(Wq, Wk, Wvd, wqkvb);
    pack_wvu<<<NH * DEMB * DH / 8 / 256, 256, 0, stream>>>(Wvu, wvub);
    init_e<<<NTOK * DEMB / 4 / 256, 256, 0, stream>>>((const float4*)x, (float4*)e, ebf);

    qkv_gemm_mfma<<<dim3(QKVW / 64, NTOK / 64), 256, 0, stream>>>(
        ebf, wqkvb, Qb[0], Kb[0], Vt[0]);

    for (int h = 0; h < NH; h++) {
        int cur = h & 1, nxt = 1 - cur;
        attn_head<<<NTOK / QT, 1024, 0, stream>>>(
            Qb[cur], Kb[cur], Vt[cur],
            Qb[nxt], Kb[nxt], Vt[nxt],
            wqkvb + (size_t)((h + 1 < NH) ? h + 1 : 0) * QKVW * DEMB,
            wvub + (size_t)h * DEMB * DH, e,
            (h == NH - 1) ? (float*)d_out : nullptr);
    }
}

// Round 11
// 456.739 us; speedup vs baseline: 1.7400x; 1.0343x over previous
//
#include <hip/hip_runtime.h>
#include <hip/hip_bf16.h>

#define NTOK 4096
#define DEMB 1024
#define NH   8
#define DH   128
#define CWIN 256
#define QKVW 384
#define SCALE 0.08838834764831845f   // 1/sqrt(128)
#define QT 16
#define NCH 34                        // 16-key chunks covering the <=527-wide band

typedef __attribute__((ext_vector_type(8))) short short8;
typedef __attribute__((ext_vector_type(4))) float floatx4;

__device__ __forceinline__ short8 pack8(float4 a, float4 b) {
    union { __hip_bfloat16 h[8]; short8 v; } o;
    o.h[0] = __float2bfloat16(a.x); o.h[1] = __float2bfloat16(a.y);
    o.h[2] = __float2bfloat16(a.z); o.h[3] = __float2bfloat16(a.w);
    o.h[4] = __float2bfloat16(b.x); o.h[5] = __float2bfloat16(b.y);
    o.h[6] = __float2bfloat16(b.z); o.h[7] = __float2bfloat16(b.w);
    return o.v;
}

// ---------------- weight prep (once per call) ----------------
__global__ void pack_wqkv(const float* __restrict__ Wq, const float* __restrict__ Wk,
                          const float* __restrict__ Wvd, __hip_bfloat16* __restrict__ dst) {
    size_t base = ((size_t)blockIdx.x * 256 + threadIdx.x) * 8;
    int k = (int)(base & 1023);
    int rh = (int)(base >> 10);
    int h = rh / QKVW;
    int row = rh - h * QKVW;
    const float* srcs[3] = {Wq, Wk, Wvd};
    const float* s = srcs[row >> 7] + (((size_t)h * DH + (row & 127)) << 10) + k;
    *(short8*)(dst + base) = pack8(*(const float4*)s, *(const float4*)(s + 4));
}

__global__ void pack_wvu(const float* __restrict__ Wvu, __hip_bfloat16* __restrict__ dst) {
    size_t base = ((size_t)blockIdx.x * 256 + threadIdx.x) * 8;
    *(short8*)(dst + base) = pack8(*(const float4*)(Wvu + base), *(const float4*)(Wvu + base + 4));
}

// ---------------- stage 0: e = x (+ bf16 mirror for head-0 qkv) -----------
__global__ void init_e(const float4* __restrict__ x, float4* __restrict__ e,
                       __hip_bfloat16* __restrict__ ebf) {
    int i = blockIdx.x * 256 + threadIdx.x;
    float4 v = x[i];
    e[i] = v;
    union { __hip_bfloat16 h[4]; uint2 u; } p;
    p.h[0] = __float2bfloat16(v.x); p.h[1] = __float2bfloat16(v.y);
    p.h[2] = __float2bfloat16(v.z); p.h[3] = __float2bfloat16(v.w);
    *(uint2*)(ebf + (size_t)i * 4) = p.u;
}

// ---------------- head-0 qkv GEMM: emits Q (scaled), K, V^T ---------------
__global__ __launch_bounds__(256) void qkv_gemm_mfma(const __hip_bfloat16* __restrict__ A,
                                                     const __hip_bfloat16* __restrict__ B,
                                                     __hip_bfloat16* __restrict__ Qb,
                                                     __hip_bfloat16* __restrict__ Kb,
                                                     __hip_bfloat16* __restrict__ Vtb) {
    constexpr int K = DEMB;
    constexpr int LDK = 40;
    const int c0 = blockIdx.x * 64, r0 = blockIdx.y * 64;
    const int tid = threadIdx.x;
    const int wave = tid >> 6, lane = tid & 63;
    const int wr = (wave >> 1) * 32, wc = (wave & 1) * 32;
    const int frow = lane & 15, kgrp = (lane >> 4) * 8;
    const int quad = lane >> 4;
    const int sr = tid >> 2, sk = (tid & 3) * 8;

    __shared__ __hip_bfloat16 As[64 * LDK];
    __shared__ __hip_bfloat16 Bs[64 * LDK];

    floatx4 acc[2][2] = {};

    for (int k0 = 0; k0 < K; k0 += 32) {
        __syncthreads();
        *(short8*)(As + sr * LDK + sk) = *(const short8*)(A + (size_t)(r0 + sr) * K + k0 + sk);
        *(short8*)(Bs + sr * LDK + sk) = *(const short8*)(B + (size_t)(c0 + sr) * K + k0 + sk);
        __syncthreads();
        short8 a0 = *(const short8*)(As + (wr + frow) * LDK + kgrp);
        short8 a1 = *(const short8*)(As + (wr + 16 + frow) * LDK + kgrp);
        short8 b0 = *(const short8*)(Bs + (wc + frow) * LDK + kgrp);
        short8 b1 = *(const short8*)(Bs + (wc + 16 + frow) * LDK + kgrp);
        acc[0][0] = __builtin_amdgcn_mfma_f32_16x16x32_bf16(a0, b0, acc[0][0], 0, 0, 0);
        acc[0][1] = __builtin_amdgcn_mfma_f32_16x16x32_bf16(a0, b1, acc[0][1], 0, 0, 0);
        acc[1][0] = __builtin_amdgcn_mfma_f32_16x16x32_bf16(a1, b0, acc[1][0], 0, 0, 0);
        acc[1][1] = __builtin_amdgcn_mfma_f32_16x16x32_bf16(a1, b1, acc[1][1], 0, 0, 0);
    }

    #pragma unroll
    for (int i = 0; i < 2; i++)
        #pragma unroll
        for (int j = 0; j < 2; j++) {
            int col = c0 + wc + j * 16 + frow;
            int row0 = r0 + wr + i * 16 + quad * 4;
            if (col < DH) {
                #pragma unroll
                for (int r = 0; r < 4; r++)
                    Qb[(size_t)(row0 + r) * DH + col] = __float2bfloat16(acc[i][j][r] * SCALE);
            } else if (col < 2 * DH) {
                #pragma unroll
                for (int r = 0; r < 4; r++)
                    Kb[(size_t)(row0 + r) * DH + col - DH] = __float2bfloat16(acc[i][j][r]);
            } else {
                union { __hip_bfloat16 h[4]; uint2 u; } p;
                #pragma unroll
                for (int r = 0; r < 4; r++) p.h[r] = __float2bfloat16(acc[i][j][r]);
                *(uint2*)(Vtb + (size_t)(col - 2 * DH) * NTOK + row0) = p.u;
            }
        }
}

// ---------------- fused head kernel: QT=16, 1024 threads (16 waves) -------
// Round-10 structure + coalesced e phase: out-proj delta bounces through LDS
// (Dbs, overlaid on dead softmax buffers), then wave w owns row w with
// float4 e reads/writes and pure-shuffle norm stats.
__global__ __launch_bounds__(1024, 4) void attn_head(const __hip_bfloat16* __restrict__ Qb,
                                                     const __hip_bfloat16* __restrict__ Kb,
                                                     const __hip_bfloat16* __restrict__ Vtb,
                                                     __hip_bfloat16* __restrict__ Qn,
                                                     __hip_bfloat16* __restrict__ Kn,
                                                     __hip_bfloat16* __restrict__ Vtn,
                                                     const __hip_bfloat16* __restrict__ Wqkv_nxt,
                                                     const __hip_bfloat16* __restrict__ Wvu,
                                                     float* __restrict__ e,
                                                     float* __restrict__ out_final) {
    // XCD swizzle: 32 token-contiguous blocks per XCD (band K/V + e-row L2
    // locality, matching the producer blocks of the previous head).
    const int vb = ((blockIdx.x & 7) << 5) | (blockIdx.x >> 3);
    const int q0 = vb * QT;
    const int tid = threadIdx.x;
    const int wave = tid >> 6, lane = tid & 63;
    const int fr = lane & 15, kg = (lane >> 4) * 8;
    const int quad = lane >> 4;
    const bool last = (out_final != nullptr);

    __shared__ alignas(16) __hip_bfloat16 Qs[QT][DH + 8];      // Q tile; later u rows
    __shared__ alignas(16) __hip_bfloat16 Ebs[QT][DEMB + 8];   // bf16 res rows (tail A)
    __shared__ alignas(16) char Ubuf[QT * 1026 * 2];           // softmax bufs / Dbs overlay

    auto Pb     = (__hip_bfloat16 (*)[NCH * 16 + 8]) Ubuf;     // 16 x 552   (17664 B)
    auto Opart  = (float (*)[64][4])(Ubuf + 17664);            // 8 x 64 x 4 ( 8192 B)
    auto statsA = (float (*)[16])(Ubuf + 17664 + 8192);        // 16 x 16    ( 1024 B)
    auto statsB = (float (*)[16])(Ubuf + 17664 + 8192 + 1024);
    auto Dbs    = (__hip_bfloat16 (*)[1026]) Ubuf;             // delta rows (32832 B)

    if (tid < 256) {   // stage Q (16x128 bf16)
        int r = tid >> 4, c8 = (tid & 15) * 8;
        *(short8*)&Qs[r][c8] = *(const short8*)(Qb + (size_t)(q0 + r) * DH + c8);
    }
    __syncthreads();
    short8 af[4];
    #pragma unroll
    for (int kc = 0; kc < 4; kc++) af[kc] = *(const short8*)&Qs[fr][kc * 32 + kg];

    const int kstart = max(q0 - CWIN, 0);
    const int kend   = min(q0 + QT - 1 + CWIN + 1, NTOK);
    const int nch = (wave < 2) ? 3 : 2;       // chunks ch = wave + 16t, ch < 34

    // ---- scores: wave's 2-3 chunks, K fragments straight from L2 ---------
    floatx4 sreg[3];
    #pragma unroll
    for (int t = 0; t < 3; t++) {
        if (t >= nch) break;
        int ch = wave + 16 * t;
        const __hip_bfloat16* krow = Kb + (size_t)(kstart + ch * 16 + fr) * DH;
        floatx4 s = {};
        #pragma unroll
        for (int kc = 0; kc < 4; kc++)
            s = __builtin_amdgcn_mfma_f32_16x16x32_bf16(af[kc],
                    *(const short8*)(krow + kc * 32 + kg), s, 0, 0, 0);
        sreg[t] = s;
    }

    // ---- band mask + per-row max ------------------------------------------
    float pmax[4] = {-1e30f, -1e30f, -1e30f, -1e30f};
    #pragma unroll
    for (int t = 0; t < 3; t++) {
        if (t >= nch) break;
        int tcol = kstart + (wave + 16 * t) * 16 + fr;
        #pragma unroll
        for (int r = 0; r < 4; r++) {
            int qg = q0 + quad * 4 + r;
            bool ok = (tcol < kend) && (tcol >= qg - CWIN) && (tcol < qg + CWIN);
            float v = ok ? sreg[t][r] : -1e30f;
            sreg[t][r] = v;
            pmax[r] = fmaxf(pmax[r], v);
        }
    }
    #pragma unroll
    for (int mm = 1; mm <= 8; mm <<= 1)
        #pragma unroll
        for (int r = 0; r < 4; r++) pmax[r] = fmaxf(pmax[r], __shfl_xor(pmax[r], mm, 64));
    if (fr == 0)
        #pragma unroll
        for (int r = 0; r < 4; r++) statsA[quad * 4 + r][wave] = pmax[r];
    __syncthreads();

    float M[4];
    #pragma unroll
    for (int r = 0; r < 4; r++) {
        int row = quad * 4 + r;
        float m = statsA[row][0];
        #pragma unroll
        for (int w = 1; w < 16; w++) m = fmaxf(m, statsA[row][w]);
        M[r] = m;
    }

    // ---- exp -> Pb (A-layout), row sums -----------------------------------
    float psum[4] = {};
    #pragma unroll
    for (int t = 0; t < 3; t++) {
        if (t >= nch) break;
        int colb = (wave + 16 * t) * 16 + fr;
        #pragma unroll
        for (int r = 0; r < 4; r++) {
            float p = __expf(sreg[t][r] - M[r]);
            psum[r] += p;
            Pb[quad * 4 + r][colb] = __float2bfloat16(p);
        }
    }
    #pragma unroll
    for (int mm = 1; mm <= 8; mm <<= 1)
        #pragma unroll
        for (int r = 0; r < 4; r++) psum[r] += __shfl_xor(psum[r], mm, 64);
    if (fr == 0)
        #pragma unroll
        for (int r = 0; r < 4; r++) statsB[quad * 4 + r][wave] = psum[r];
    __syncthreads();

    // ---- PV split in two kc-halves: wave = half*8 + dim-group -------------
    const int g = wave & 7, half = wave >> 3;
    {
        floatx4 Of = {};
        const int kc0 = half ? 9 : 0, kc1 = half ? 17 : 9;
        for (int kc = kc0; kc < kc1; kc++) {
            short8 pf = *(const short8*)&Pb[fr][kc * 32 + kg];
            const __hip_bfloat16* vrow = Vtb + (size_t)(g * 16 + fr) * NTOK
                                       + kstart + kc * 32 + kg;
            Of = __builtin_amdgcn_mfma_f32_16x16x32_bf16(pf, *(const short8*)vrow, Of, 0, 0, 0);
        }
        if (half) *(float4*)&Opart[g][lane][0] = *(float4*)&Of;
        __syncthreads();
        if (!half) {
            float4 o2 = *(const float4*)&Opart[g][lane][0];
            float linv[4];
            #pragma unroll
            for (int r = 0; r < 4; r++) {
                int row = quad * 4 + r;
                float s = 0.f;
                #pragma unroll
                for (int w = 0; w < 16; w++) s += statsB[row][w];
                linv[r] = 1.0f / s;
            }
            int col = g * 16 + fr;
            Qs[quad * 4 + 0][col] = __float2bfloat16((Of[0] + o2.x) * linv[0]);
            Qs[quad * 4 + 1][col] = __float2bfloat16((Of[1] + o2.y) * linv[1]);
            Qs[quad * 4 + 2][col] = __float2bfloat16((Of[2] + o2.z) * linv[2]);
            Qs[quad * 4 + 3][col] = __float2bfloat16((Of[3] + o2.w) * linv[3]);
        }
    }
    __syncthreads();                   // u rows ready; Pb/Opart/stats now DEAD
    short8 af2[4];
    #pragma unroll
    for (int kc = 0; kc < 4; kc++) af2[kc] = *(const short8*)&Qs[fr][kc * 32 + kg];

    // ---- out-proj: wave owns cols [64w, 64w+64); delta -> Dbs (bf16) ------
    {
        floatx4 accd[4] = {};
        #pragma unroll
        for (int n0 = 0; n0 < 4; n0++) {
            const __hip_bfloat16* wrow = Wvu + ((size_t)(wave * 64 + n0 * 16 + fr) << 7);
            #pragma unroll
            for (int kc = 0; kc < 4; kc++)
                accd[n0] = __builtin_amdgcn_mfma_f32_16x16x32_bf16(af2[kc],
                               *(const short8*)(wrow + kc * 32 + kg), accd[n0], 0, 0, 0);
        }
        #pragma unroll
        for (int n0 = 0; n0 < 4; n0++) {
            int col = wave * 64 + n0 * 16 + fr;
            #pragma unroll
            for (int r = 0; r < 4; r++)
                Dbs[quad * 4 + r][col] = __float2bfloat16(accd[n0][r]);
        }
    }
    __syncthreads();                   // Dbs complete

    // ---- row-per-wave norm: wave w owns row w; float4 coalesced -----------
    {
        const size_t rowbase = (size_t)(q0 + wave) * DEMB;
        float4 ev[4];
        float od[16];
        float s1 = 0.f, s2 = 0.f;
        #pragma unroll
        for (int j = 0; j < 4; j++) {
            int c4 = (j * 64 + lane) * 4;
            ev[j] = *(const float4*)(e + rowbase + c4);
            union { uint2 u; __hip_bfloat16 h[4]; } dp;
            dp.u = *(const uint2*)&Dbs[wave][c4];
            od[j * 4 + 0] = ev[j].x + __bfloat162float(dp.h[0]);
            od[j * 4 + 1] = ev[j].y + __bfloat162float(dp.h[1]);
            od[j * 4 + 2] = ev[j].z + __bfloat162float(dp.h[2]);
            od[j * 4 + 3] = ev[j].w + __bfloat162float(dp.h[3]);
            #pragma unroll
            for (int c = 0; c < 4; c++) { s1 += od[j * 4 + c]; s2 += od[j * 4 + c] * od[j * 4 + c]; }
        }
        #pragma unroll
        for (int mm = 1; mm <= 32; mm <<= 1) {
            s1 += __shfl_xor(s1, mm, 64);
            s2 += __shfl_xor(s2, mm, 64);
        }
        float m0 = s1 * (1.0f / DEMB);
        float iv = 1.0f / m0;
        float m  = m0 * iv;                        // mean(out/m0) ~ 1
        float st = s1 * iv;
        float var = (s2 * iv * iv - st * st * (1.0f / DEMB)) * (1.0f / (DEMB - 1));
        float isd = rsqrtf(var);

        #pragma unroll
        for (int j = 0; j < 4; j++) {
            int c4 = (j * 64 + lane) * 4;
            float4 res;
            res.x = ev[j].x + (od[j * 4 + 0] * iv - m) * isd + m;
            res.y = ev[j].y + (od[j * 4 + 1] * iv - m) * isd + m;
            res.z = ev[j].z + (od[j * 4 + 2] * iv - m) * isd + m;
            res.w = ev[j].w + (od[j * 4 + 3] * iv - m) * isd + m;
            if (last) {
                float4 o = make_float4(res.x * 0.125f, res.y * 0.125f,
                                       res.z * 0.125f, res.w * 0.125f);
                *(float4*)(out_final + rowbase + c4) = o;
            } else {
                *(float4*)(e + rowbase + c4) = res;
                union { __hip_bfloat16 h[4]; uint2 u; } p;
                p.h[0] = __float2bfloat16(res.x); p.h[1] = __float2bfloat16(res.y);
                p.h[2] = __float2bfloat16(res.z); p.h[3] = __float2bfloat16(res.w);
                *(uint2*)&Ebs[wave][c4] = p.u;
            }
        }
    }

    // ---- fused next-head QKV: 24 N-tiles over 16 waves (1-2 each) ---------
    if (!last) {
        __syncthreads();               // Ebs complete
        const int nt = (wave < 8) ? 2 : 1;    // tiles n = wave + 16t, n < 24
        floatx4 acc2[2] = {};
        #pragma unroll 8
        for (int kc = 0; kc < 32; kc++) {
            short8 a = *(const short8*)&Ebs[fr][kc * 32 + kg];
            #pragma unroll
            for (int t = 0; t < 2; t++) {
                if (t >= nt) break;
                int n = wave + 16 * t;
                acc2[t] = __builtin_amdgcn_mfma_f32_16x16x32_bf16(a,
                              *(const short8*)(Wqkv_nxt + (size_t)(n * 16 + fr) * DEMB
                                               + kc * 32 + kg),
                              acc2[t], 0, 0, 0);
            }
        }
        const int row0 = q0 + quad * 4;
        #pragma unroll
        for (int t = 0; t < 2; t++) {
            if (t >= nt) break;
            int n = wave + 16 * t;
            if (n < 8) {               // Q, pre-scaled
                int col = n * 16 + fr;
                #pragma unroll
                for (int rr = 0; rr < 4; rr++)
                    Qn[(size_t)(row0 + rr) * DH + col] = __float2bfloat16(acc2[t][rr] * SCALE);
            } else if (n < 16) {       // K
                int col = (n - 8) * 16 + fr;
                #pragma unroll
                for (int rr = 0; rr < 4; rr++)
                    Kn[(size_t)(row0 + rr) * DH + col] = __float2bfloat16(acc2[t][rr]);
            } else {                   // V^T
                int d = (n - 16) * 16 + fr;
                union { __hip_bfloat16 h[4]; uint2 u; } p;
                #pragma unroll
                for (int rr = 0; rr < 4; rr++) p.h[rr] = __float2bfloat16(acc2[t][rr]);
                *(uint2*)(Vtn + (size_t)d * NTOK + row0) = p.u;
            }
        }
    }
}

extern "C" void kernel_launch(void* const* d_in, const int* in_sizes, int n_in,
                              void* d_out, int out_size, void* d_ws, size_t ws_size,
                              hipStream_t stream) {
    const float* x   = (const float*)d_in[0];
    const float* Wq  = (const float*)d_in[1];
    const float* Wk  = (const float*)d_in[2];
    const float* Wvd = (const float*)d_in[3];
    const float* Wvu = (const float*)d_in[4];

    char* ws = (char*)d_ws;
    float* e = (float*)ws;                                              // 16 MB
    __hip_bfloat16* ebf   = (__hip_bfloat16*)(ws + (16u << 20));        //  8 MB (head-0 prologue only)
    __hip_bfloat16* Qb[2] = {(__hip_bfloat16*)(ws + (24u << 20)),
                             (__hip_bfloat16*)(ws + (27u << 20))};      //  1 MB each
    __hip_bfloat16* Kb[2] = {(__hip_bfloat16*)(ws + (25u << 20)),
                             (__hip_bfloat16*)(ws + (28u << 20))};
    __hip_bfloat16* Vt[2] = {(__hip_bfloat16*)(ws + (26u << 20)),
                             (__hip_bfloat16*)(ws + (29u << 20))};
    __hip_bfloat16* wqkvb = (__hip_bfloat16*)(ws + (30u << 20));        //  6 MB
    __hip_bfloat16* wvub  = (__hip_bfloat16*)(ws + (36u << 20));        //  2 MB  -> 38 MB

    pack_wqkv<<<NH * QKVW * DEMB / 8 / 256, 256, 0, stream>>>(Wq, Wk, Wvd, wqkvb);
    pack_wvu<<<NH * DEMB * DH / 8 / 256, 256, 0, stream>>>(Wvu, wvub);
    init_e<<<NTOK * DEMB / 4 / 256, 256, 0, stream>>>((const float4*)x, (float4*)e, ebf);

    qkv_gemm_mfma<<<dim3(QKVW / 64, NTOK / 64), 256, 0, stream>>>(
        ebf, wqkvb, Qb[0], Kb[0], Vt[0]);

    for (int h = 0; h < NH; h++) {
        int cur = h & 1, nxt = 1 - cur;
        attn_head<<<NTOK / QT, 1024, 0, stream>>>(
            Qb[cur], Kb[cur], Vt[cur],
            Qb[nxt], Kb[nxt], Vt[nxt],
            wqkvb + (size_t)((h + 1 < NH) ? h + 1 : 0) * QKVW * DEMB,
            wvub + (size_t)h * DEMB * DH, e,
            (h == NH - 1) ? (float*)d_out : nullptr);
    }
}